// Round 3
// baseline (282.747 us; speedup 1.0000x reference)
//
#include <hip/hip_runtime.h>
#include <hip/hip_bf16.h>
#include <math.h>

// Problem: mu-law compress -> 6-bit quantize -> decompress, plus per-row SNR.
// x: (65536, 512) f32. Outputs: yd (same shape) then snr scalar, concatenated.

#define NROWS 65536
#define DCOL  512
#define ROWS_PER_BLOCK 4
#define NBLOCKS (NROWS / ROWS_PER_BLOCK)   // 16384

// ln(51) and friends as f32 constants (reference: math.log(1+50) folded to f32 by jax)
#define LOG1MU     3.9318256327243257f
#define INV_LOG1MU (1.0f / 3.9318256327243257f)
#define INV_MU     0.02f
#define INV63      (1.0f / 63.0f)

__device__ __forceinline__ float process_one(float xi, float& sx, float& se) {
    float xm = fmaf(2.0f, xi, -1.0f);
    float s  = (xm > 0.0f) ? 1.0f : -1.0f;
    float a  = fabsf(xm);
    // compress
    float xc = log1pf(50.0f * a) * INV_LOG1MU;      // in [0,1]
    // quantize: searchsorted(midpoints, xc) == round-half-down(xc*63)
    int idx = (int)floorf(fmaf(xc, 63.0f, 0.5f));
    idx = idx < 0 ? 0 : (idx > 63 ? 63 : idx);
    float y = (float)idx * INV63;
    // decompress
    float da  = (expf(y * LOG1MU) - 1.0f) * INV_MU; // in [0,1]
    float out = fmaf(s * da, 0.5f, 0.5f);
    sx = fmaf(xi, xi, sx);
    float e = xi - out;
    se = fmaf(e, e, se);
    return out;
}

__global__ __launch_bounds__(256) void quant_main(const float* __restrict__ x,
                                                  float* __restrict__ yd,
                                                  float* __restrict__ partial) {
    const int wave = threadIdx.x >> 6;   // 0..3
    const int lane = threadIdx.x & 63;
    const int row  = blockIdx.x * ROWS_PER_BLOCK + wave;

    const float4* __restrict__ xr = (const float4*)(x  + (size_t)row * DCOL);
    float4*       __restrict__ yr = (float4*)      (yd + (size_t)row * DCOL);

    float sx = 0.0f, se = 0.0f;

#pragma unroll
    for (int h = 0; h < 2; ++h) {
        float4 v = xr[h * 64 + lane];
        float4 o;
        o.x = process_one(v.x, sx, se);
        o.y = process_one(v.y, sx, se);
        o.z = process_one(v.z, sx, se);
        o.w = process_one(v.w, sx, se);
        yr[h * 64 + lane] = o;
    }

    // wave-level (64-lane) reduction of sx, se
#pragma unroll
    for (int off = 32; off >= 1; off >>= 1) {
        sx += __shfl_xor(sx, off);
        se += __shfl_xor(se, off);
    }

    __shared__ float ls[ROWS_PER_BLOCK];
    if (lane == 0) {
        // ||x|| / ||x - yd|| = sqrt(sx/se); pre-scale by 1/NROWS for the mean
        ls[wave] = sqrtf(sx / se) * (1.0f / (float)NROWS);
    }
    __syncthreads();
    if (threadIdx.x == 0) {
        partial[blockIdx.x] = ls[0] + ls[1] + ls[2] + ls[3];
    }
}

__global__ __launch_bounds__(256) void snr_reduce(const float* __restrict__ partial,
                                                  float* __restrict__ snr_out) {
    __shared__ float s[256];
    float acc = 0.0f;
    for (int i = threadIdx.x; i < NBLOCKS; i += 256) acc += partial[i];
    s[threadIdx.x] = acc;
    __syncthreads();
#pragma unroll
    for (int off = 128; off >= 1; off >>= 1) {
        if (threadIdx.x < off) s[threadIdx.x] += s[threadIdx.x + off];
        __syncthreads();
    }
    if (threadIdx.x == 0) snr_out[0] = s[0];
}

extern "C" void kernel_launch(void* const* d_in, const int* in_sizes, int n_in,
                              void* d_out, int out_size, void* d_ws, size_t ws_size,
                              hipStream_t stream) {
    const float* x = (const float*)d_in[0];
    // d_in[1] = thrs (63), d_in[2] = levels (64) — known analytically, unused.
    float* yd      = (float*)d_out;
    float* snr_out = (float*)d_out + (size_t)NROWS * DCOL;
    float* partial = (float*)d_ws;   // 16384 floats = 64 KB

    quant_main<<<NBLOCKS, 256, 0, stream>>>(x, yd, partial);
    snr_reduce<<<1, 256, 0, stream>>>(partial, snr_out);
}

// Round 7
// 249.575 us; speedup vs baseline: 1.1329x; 1.1329x over previous
//
#include <hip/hip_runtime.h>
#include <hip/hip_bf16.h>
#include <math.h>

// mu-law compress -> 6-bit quantize -> decompress + per-row SNR.
// x: (65536, 512) f32. Outputs: yd (same shape) then snr scalar, concatenated.
//
// R3 finding: libm log1pf/expf made the kernel VALU-bound (118us, VALUBusy 115%).
// Fix: single hw-TRANS ops. idx = floor(log2(1+50a) * 63/log2(51) + 0.5) is the
// same searchsorted bin (boundary FP ties may flip one bin = 0.031 in yd, the
// already-accepted error mode). Dequant via __expf (v_exp_f32).

#define NROWS 65536
#define DCOL  512
#define ROWS_PER_BLOCK 4
#define NBLOCKS (NROWS / ROWS_PER_BLOCK)   // 16384

#define K_IDX  11.1063604f    // 63 / log2(51)
#define K_EXP  0.0624099307f  // ln(51) / 63

__device__ __forceinline__ float process_one(float xi, float& sx, float& se) {
    float xm = fmaf(2.0f, xi, -1.0f);
    float s  = (xm > 0.0f) ? 0.5f : -0.5f;
    float a  = fabsf(xm);
    float w  = fmaf(50.0f, a, 1.0f);              // 1 + mu*|xm|, in [1,51]
    float qf = floorf(fmaf(__log2f(w), K_IDX, 0.5f));  // quant index as float
    float e2 = __expf(qf * K_EXP);                // 51^(idx/63)
    float da = fmaf(e2, 0.02f, -0.02f);           // (51^(idx/63)-1)/50
    float out = fmaf(s, da, 0.5f);
    sx = fmaf(xi, xi, sx);
    float e = xi - out;
    se = fmaf(e, e, se);
    return out;
}

__global__ __launch_bounds__(256) void quant_main(const float* __restrict__ x,
                                                  float* __restrict__ yd,
                                                  float* __restrict__ partial) {
    const int wave = threadIdx.x >> 6;   // 0..3
    const int lane = threadIdx.x & 63;
    const int row  = blockIdx.x * ROWS_PER_BLOCK + wave;

    const float4* __restrict__ xr = (const float4*)(x  + (size_t)row * DCOL);
    float4*       __restrict__ yr = (float4*)      (yd + (size_t)row * DCOL);

    float sx = 0.0f, se = 0.0f;

#pragma unroll
    for (int h = 0; h < 2; ++h) {
        float4 v = xr[h * 64 + lane];
        float4 o;
        o.x = process_one(v.x, sx, se);
        o.y = process_one(v.y, sx, se);
        o.z = process_one(v.z, sx, se);
        o.w = process_one(v.w, sx, se);
        yr[h * 64 + lane] = o;
    }

    // wave-level (64-lane) reduction of sx, se
#pragma unroll
    for (int off = 32; off >= 1; off >>= 1) {
        sx += __shfl_xor(sx, off);
        se += __shfl_xor(se, off);
    }

    __shared__ float ls[ROWS_PER_BLOCK];
    if (lane == 0) {
        // ||x|| / ||x - yd|| = sqrt(sx/se); pre-scale by 1/NROWS for the mean
        ls[wave] = sqrtf(sx / se) * (1.0f / (float)NROWS);
    }
    __syncthreads();
    if (threadIdx.x == 0) {
        partial[blockIdx.x] = ls[0] + ls[1] + ls[2] + ls[3];
    }
}

__global__ __launch_bounds__(256) void snr_reduce(const float* __restrict__ partial,
                                                  float* __restrict__ snr_out) {
    __shared__ float s[256];
    float acc = 0.0f;
    for (int i = threadIdx.x; i < NBLOCKS; i += 256) acc += partial[i];
    s[threadIdx.x] = acc;
    __syncthreads();
#pragma unroll
    for (int off = 128; off >= 1; off >>= 1) {
        if (threadIdx.x < off) s[threadIdx.x] += s[threadIdx.x + off];
        __syncthreads();
    }
    if (threadIdx.x == 0) snr_out[0] = s[0];
}

extern "C" void kernel_launch(void* const* d_in, const int* in_sizes, int n_in,
                              void* d_out, int out_size, void* d_ws, size_t ws_size,
                              hipStream_t stream) {
    const float* x = (const float*)d_in[0];
    // d_in[1] = thrs (63), d_in[2] = levels (64) — known analytically, unused.
    float* yd      = (float*)d_out;
    float* snr_out = (float*)d_out + (size_t)NROWS * DCOL;
    float* partial = (float*)d_ws;   // 16384 floats = 64 KB

    quant_main<<<NBLOCKS, 256, 0, stream>>>(x, yd, partial);
    snr_reduce<<<1, 256, 0, stream>>>(partial, snr_out);
}

// Round 9
// 241.739 us; speedup vs baseline: 1.1696x; 1.0324x over previous
//
#include <hip/hip_runtime.h>
#include <hip/hip_bf16.h>
#include <math.h>

// mu-law compress -> 6-bit quantize -> decompress + per-row SNR.
// x: (65536, 512) f32. Outputs: yd (same shape) then snr scalar, concatenated.
//
// R3: libm log1pf/expf -> VALU-bound, 118us (VALUBusy 115%).
// R7: hw TRANS (__log2f/__expf) -> <79us; compute ~9us vs memory ~40us, so
//     ~75us means LATENCY-bound: only 2 loads in flight per lane.
// R8/R9: 4 rows per wave = 8 independent float4 loads in flight per lane
//     (4x MLP), copysignf, nontemporal stores via clang ext_vector_type
//     (HIP float4 is a struct -> rejected by __builtin_nontemporal_store).

#define NROWS 65536
#define DCOL  512
#define ROWS_PER_WAVE 4
#define WAVES_PER_BLOCK 4
#define ROWS_PER_BLOCK (ROWS_PER_WAVE * WAVES_PER_BLOCK)   // 16
#define NBLOCKS (NROWS / ROWS_PER_BLOCK)                   // 4096

#define K_IDX  11.1063604f    // 63 / log2(51)
#define K_EXP  0.0624099307f  // ln(51) / 63

typedef float vfloat4 __attribute__((ext_vector_type(4)));

__device__ __forceinline__ void process4(vfloat4 v, vfloat4& o, float& sx, float& se) {
#pragma unroll
    for (int k = 0; k < 4; ++k) {
        float xi = v[k];
        float xm = fmaf(2.0f, xi, -1.0f);
        float w  = fmaf(50.0f, fabsf(xm), 1.0f);             // 1+mu|xm| in [1,51]
        float qf = floorf(fmaf(__log2f(w), K_IDX, 0.5f));    // quant index
        float e2 = __expf(qf * K_EXP);                       // 51^(idx/63)
        float da = fmaf(e2, 0.01f, -0.01f);                  // 0.01*(e2-1) >= 0
        float out = 0.5f + copysignf(da, xm);                // sign via v_bfi
        sx = fmaf(xi, xi, sx);
        float e = xi - out;
        se = fmaf(e, e, se);
        o[k] = out;
    }
}

__global__ __launch_bounds__(256) void quant_main(const float* __restrict__ x,
                                                  float* __restrict__ yd,
                                                  float* __restrict__ partial) {
    const int wave = threadIdx.x >> 6;   // 0..3
    const int lane = threadIdx.x & 63;
    const int row0 = (blockIdx.x * WAVES_PER_BLOCK + wave) * ROWS_PER_WAVE;

    const vfloat4* __restrict__ xr[ROWS_PER_WAVE];
    vfloat4*       __restrict__ yr[ROWS_PER_WAVE];
#pragma unroll
    for (int r = 0; r < ROWS_PER_WAVE; ++r) {
        xr[r] = (const vfloat4*)(x  + (size_t)(row0 + r) * DCOL);
        yr[r] = (vfloat4*)      (yd + (size_t)(row0 + r) * DCOL);
    }

    // Issue all 8 independent 16B loads before any compute (MLP).
    vfloat4 va[ROWS_PER_WAVE], vb[ROWS_PER_WAVE];
#pragma unroll
    for (int r = 0; r < ROWS_PER_WAVE; ++r) {
        va[r] = xr[r][lane];
        vb[r] = xr[r][64 + lane];
    }

    float sx[ROWS_PER_WAVE], se[ROWS_PER_WAVE];
#pragma unroll
    for (int r = 0; r < ROWS_PER_WAVE; ++r) { sx[r] = 0.0f; se[r] = 0.0f; }

#pragma unroll
    for (int r = 0; r < ROWS_PER_WAVE; ++r) {
        vfloat4 oa, ob;
        process4(va[r], oa, sx[r], se[r]);
        process4(vb[r], ob, sx[r], se[r]);
        __builtin_nontemporal_store(oa, &yr[r][lane]);
        __builtin_nontemporal_store(ob, &yr[r][64 + lane]);
    }

    // Per-row wave reduction (64 lanes) of sx, se; accumulate snr partial.
    float acc = 0.0f;
#pragma unroll
    for (int r = 0; r < ROWS_PER_WAVE; ++r) {
        float s1 = sx[r], s2 = se[r];
#pragma unroll
        for (int off = 32; off >= 1; off >>= 1) {
            s1 += __shfl_xor(s1, off);
            s2 += __shfl_xor(s2, off);
        }
        acc += sqrtf(s1 / s2);
    }

    __shared__ float ls[WAVES_PER_BLOCK];
    if (lane == 0) ls[wave] = acc * (1.0f / (float)NROWS);
    __syncthreads();
    if (threadIdx.x == 0) {
        partial[blockIdx.x] = ls[0] + ls[1] + ls[2] + ls[3];
    }
}

__global__ __launch_bounds__(256) void snr_reduce(const float* __restrict__ partial,
                                                  float* __restrict__ snr_out) {
    __shared__ float s[256];
    float acc = 0.0f;
    for (int i = threadIdx.x; i < NBLOCKS; i += 256) acc += partial[i];
    s[threadIdx.x] = acc;
    __syncthreads();
#pragma unroll
    for (int off = 128; off >= 1; off >>= 1) {
        if (threadIdx.x < off) s[threadIdx.x] += s[threadIdx.x + off];
        __syncthreads();
    }
    if (threadIdx.x == 0) snr_out[0] = s[0];
}

extern "C" void kernel_launch(void* const* d_in, const int* in_sizes, int n_in,
                              void* d_out, int out_size, void* d_ws, size_t ws_size,
                              hipStream_t stream) {
    const float* x = (const float*)d_in[0];
    // d_in[1] = thrs (63), d_in[2] = levels (64) — known analytically, unused.
    float* yd      = (float*)d_out;
    float* snr_out = (float*)d_out + (size_t)NROWS * DCOL;
    float* partial = (float*)d_ws;   // 4096 floats = 16 KB

    quant_main<<<NBLOCKS, 256, 0, stream>>>(x, yd, partial);
    snr_reduce<<<1, 256, 0, stream>>>(partial, snr_out);
}